// Round 1
// baseline (995.900 us; speedup 1.0000x reference)
//
#include <hip/hip_runtime.h>
#include <hip/hip_bf16.h>
#include <cstddef>

#define B_ 8
#define C_ 128
#define CH_ 64
#define H_ 64
#define W_ 64
#define HW_ 4096
#define S_ 256
#define HEADS_ 4
#define HD_ 16

// ---------------- workspace layout (floats) ----------------
// Fl    [B][4096][64]   @ 0          size 2,097,152
// QKVl  [B][4096][192]  @ 2,097,152  size 6,291,456
// Fg    [B][256][64]    @ 8,388,608  size 131,072
// QKVg  [B][256][192]   @ 8,519,680  size 393,216
// Flg   [B][64][4096]   @ 8,912,896  size 2,097,152
// Fgl   [B][64][256]    @ 11,010,048 size 131,072
// Fglup [B][64][4096]   @ 11,141,120 size 2,097,152
// WT    [128][128]      @ 13,238,272 size 16,384
#define OF_FL     0
#define OF_QKVL   2097152
#define OF_FG     8388608
#define OF_QKVG   8519680
#define OF_FLG    8912896
#define OF_FGL    11010048
#define OF_FGLUP  11141120
#define OF_WT     13238272

// ---------------- K1: 3x3 depthwise-block conv + BN + ReLU ----------------
// grid: b(8) x tile(16) x cgroup(2) = 256 blocks, 256 threads (16x16 pixels)
__global__ __launch_bounds__(256) void k_depconv(
    const float* __restrict__ in, const float* __restrict__ w,
    const float* __restrict__ scale, const float* __restrict__ bias,
    float* __restrict__ Fl)
{
    const int cg   = blockIdx.x & 1;
    const int tile = (blockIdx.x >> 1) & 15;
    const int b    = blockIdx.x >> 5;
    const int ty0 = (tile >> 2) * 16, tx0 = (tile & 3) * 16;
    const int px = threadIdx.x & 15, py = threadIdx.x >> 4;
    const int y = ty0 + py, x = tx0 + px;

    __shared__ float t[18][18];
    float acc[32];
#pragma unroll
    for (int i = 0; i < 32; ++i) acc[i] = 0.f;

    const float* inb = in + (size_t)b * C_ * HW_;

    for (int ci = 0; ci < 64; ++ci) {
        const float* p = inb + (size_t)ci * HW_;
        for (int idx = threadIdx.x; idx < 324; idx += 256) {
            int ly = idx / 18, lx = idx - ly * 18;
            int gy = ty0 + ly - 1, gx = tx0 + lx - 1;
            float v = 0.f;
            if (gy >= 0 && gy < 64 && gx >= 0 && gx < 64) v = p[gy * 64 + gx];
            t[ly][lx] = v;
        }
        __syncthreads();
        float i00 = t[py][px],     i01 = t[py][px + 1],     i02 = t[py][px + 2];
        float i10 = t[py + 1][px], i11 = t[py + 1][px + 1], i12 = t[py + 1][px + 2];
        float i20 = t[py + 2][px], i21 = t[py + 2][px + 1], i22 = t[py + 2][px + 2];
        const int wbase = cg * 18432 + ci * 9;   // ((cg*32+i)*64+ci)*9 = wbase + i*576
#pragma unroll
        for (int i = 0; i < 32; ++i) {
            const float* wp = w + wbase + i * 576;
            acc[i] += i00 * wp[0] + i01 * wp[1] + i02 * wp[2]
                    + i10 * wp[3] + i11 * wp[4] + i12 * wp[5]
                    + i20 * wp[6] + i21 * wp[7] + i22 * wp[8];
        }
        __syncthreads();
    }
    const int n = y * 64 + x;
    float* out = Fl + ((size_t)b * HW_ + n) * 64 + cg * 32;
#pragma unroll
    for (int i = 0; i < 32; ++i) {
        float v = acc[i] * scale[cg * 32 + i] + bias[cg * 32 + i];
        out[i] = v > 0.f ? v : 0.f;
    }
}

// ---------------- K2: 4x4 mean pool of channels 64..127 ----------------
__global__ __launch_bounds__(256) void k_pool(const float* __restrict__ in,
                                              float* __restrict__ Fg)
{
    int idx = blockIdx.x * 256 + threadIdx.x;   // 8*256*64 = 131072
    int c = idx & 63, s = (idx >> 6) & 255, b = idx >> 14;
    int sy = s >> 4, sx = s & 15;
    const float* p = in + ((size_t)b * C_ + 64 + c) * HW_ + (sy * 4) * 64 + sx * 4;
    float sum = 0.f;
#pragma unroll
    for (int dy = 0; dy < 4; ++dy)
#pragma unroll
        for (int dx = 0; dx < 4; ++dx) sum += p[dy * 64 + dx];
    Fg[((size_t)b * S_ + s) * 64 + c] = sum * (1.f / 16.f);
}

// ---------------- K3: QKV GEMM  out[M][192] = feat[M][64] @ W^T + b ------
__global__ __launch_bounds__(256) void k_qkv(const float* __restrict__ feat,
                                             const float* __restrict__ Wq,
                                             const float* __restrict__ bias,
                                             float* __restrict__ out, int M)
{
    int idx = blockIdx.x * 256 + threadIdx.x;
    int r = idx / 48;
    int j4 = (idx - r * 48) * 4;
    if (r >= M) return;
    const float4* f4 = (const float4*)(feat + (size_t)r * 64);
    float a0 = bias[j4], a1 = bias[j4 + 1], a2 = bias[j4 + 2], a3 = bias[j4 + 3];
    const float4* w0 = (const float4*)(Wq + (size_t)j4 * 64);
    const float4* w1 = (const float4*)(Wq + (size_t)(j4 + 1) * 64);
    const float4* w2 = (const float4*)(Wq + (size_t)(j4 + 2) * 64);
    const float4* w3 = (const float4*)(Wq + (size_t)(j4 + 3) * 64);
#pragma unroll
    for (int k = 0; k < 16; ++k) {
        float4 f = f4[k];
        float4 wa = w0[k], wb = w1[k], wc = w2[k], wd = w3[k];
        a0 += f.x * wa.x + f.y * wa.y + f.z * wa.z + f.w * wa.w;
        a1 += f.x * wb.x + f.y * wb.y + f.z * wb.z + f.w * wb.w;
        a2 += f.x * wc.x + f.y * wc.y + f.z * wc.z + f.w * wc.w;
        a3 += f.x * wd.x + f.y * wd.y + f.z * wd.z + f.w * wd.w;
    }
    float4 r4; r4.x = a0; r4.y = a1; r4.z = a2; r4.w = a3;
    *(float4*)(out + (size_t)r * 192 + j4) = r4;
}

// ---------------- K4: attn_lg (local queries attend to 256 global keys) ---
// grid: b(8) x h(4) x qt(16) = 512 blocks, 256 threads, 1 query/thread
__global__ __launch_bounds__(256) void k_attn_lg(const float* __restrict__ qkvl,
                                                 const float* __restrict__ qkvg,
                                                 float* __restrict__ Flg)
{
    int qt = blockIdx.x & 15, h = (blockIdx.x >> 4) & 3, b = blockIdx.x >> 6;
    int q = qt * 256 + threadIdx.x;
    const float* qp = qkvl + ((size_t)(b * HW_ + q)) * 192 + h * 16;
    float qv[16];
#pragma unroll
    for (int d = 0; d < 16; ++d) qv[d] = qp[d];
    const float* kbase = qkvg + (size_t)b * S_ * 192 + 64 + h * 16;
    const float* vbase = kbase + 64;

    float m = -1e30f;
    for (int s = 0; s < S_; ++s) {
        const float* kp = kbase + s * 192;
        float dot = 0.f;
#pragma unroll
        for (int d = 0; d < 16; ++d) dot += qv[d] * kp[d];
        m = fmaxf(m, dot);
    }
    float l = 0.f, o[16];
#pragma unroll
    for (int d = 0; d < 16; ++d) o[d] = 0.f;
    for (int s = 0; s < S_; ++s) {
        const float* kp = kbase + s * 192;
        float dot = 0.f;
#pragma unroll
        for (int d = 0; d < 16; ++d) dot += qv[d] * kp[d];
        float p = __expf((dot - m) * 0.25f);
        l += p;
        const float* vp = vbase + s * 192;
#pragma unroll
        for (int d = 0; d < 16; ++d) o[d] += p * vp[d];
    }
    float inv = 1.f / l;
    float* outp = Flg + (size_t)b * 64 * HW_ + (size_t)(h * 16) * HW_ + q;
#pragma unroll
    for (int d = 0; d < 16; ++d) outp[(size_t)d * HW_] = o[d] * inv;
}

// ---------------- K5: attn_gl (256 global queries attend to 4096 local) ---
// block: 32 queries x 8 key-parts; grid: b(8) x h(4) x qc(8) = 256 blocks
__global__ __launch_bounds__(256) void k_attn_gl(const float* __restrict__ qkvl,
                                                 const float* __restrict__ qkvg,
                                                 float* __restrict__ Fgl)
{
    int qc = blockIdx.x & 7, h = (blockIdx.x >> 3) & 3, b = blockIdx.x >> 5;
    int part = threadIdx.x & 7, ql = threadIdx.x >> 3;   // ql: 0..31
    int s = qc * 32 + ql;
    const float* qp = qkvg + ((size_t)(b * S_ + s)) * 192 + h * 16;
    float qv[16];
#pragma unroll
    for (int d = 0; d < 16; ++d) qv[d] = qp[d];
    const float* kbase = qkvl + (size_t)b * HW_ * 192 + 64 + h * 16;
    const float* vbase = kbase + 64;

    float m = -1e30f, l = 0.f, o[16];
#pragma unroll
    for (int d = 0; d < 16; ++d) o[d] = 0.f;

    for (int j = 0; j < 512; ++j) {
        int key = j * 8 + part;
        const float* kp = kbase + (size_t)key * 192;
        float dot = 0.f;
#pragma unroll
        for (int d = 0; d < 16; ++d) dot += qv[d] * kp[d];
        float sc = dot * 0.25f;
        if (sc > m) {
            float f = __expf(m - sc);
            l *= f;
#pragma unroll
            for (int d = 0; d < 16; ++d) o[d] *= f;
            m = sc;
        }
        float p = __expf(sc - m);
        l += p;
        const float* vp = vbase + (size_t)key * 192;
#pragma unroll
        for (int d = 0; d < 16; ++d) o[d] += p * vp[d];
    }

    __shared__ float sm[32][8], sl[32][8], so[32][8][16];
    sm[ql][part] = m; sl[ql][part] = l;
#pragma unroll
    for (int d = 0; d < 16; ++d) so[ql][part][d] = o[d];
    __syncthreads();

    if (part == 0) {
        float M = -1e30f;
#pragma unroll
        for (int pp = 0; pp < 8; ++pp) M = fmaxf(M, sm[ql][pp]);
        float L = 0.f, O[16];
#pragma unroll
        for (int d = 0; d < 16; ++d) O[d] = 0.f;
#pragma unroll
        for (int pp = 0; pp < 8; ++pp) {
            float f = __expf(sm[ql][pp] - M);
            L += sl[ql][pp] * f;
#pragma unroll
            for (int d = 0; d < 16; ++d) O[d] += so[ql][pp][d] * f;
        }
        float inv = 1.f / L;
        float* outp = Fgl + (size_t)b * 64 * S_ + (size_t)(h * 16) * S_ + s;
#pragma unroll
        for (int d = 0; d < 16; ++d) outp[d * S_] = O[d] * inv;
    }
}

// ---------------- K6: bilinear upsample 16x16 -> 64x64 (half-pixel, clamp) -
__global__ __launch_bounds__(256) void k_up(const float* __restrict__ Fgl,
                                            float* __restrict__ up)
{
    int idx = blockIdx.x * 256 + threadIdx.x;   // B*64*4096
    int x = idx & 63, y = (idx >> 6) & 63, bc = idx >> 12;
    float sy = y * 0.25f - 0.375f, sx = x * 0.25f - 0.375f;
    float fy0 = floorf(sy), fx0 = floorf(sx);
    int y0 = (int)fy0, x0 = (int)fx0;
    float fy = sy - fy0, fx = sx - fx0;
    int ya = y0 < 0 ? 0 : y0, yb = y0 + 1 > 15 ? 15 : y0 + 1;
    int xa = x0 < 0 ? 0 : x0, xb = x0 + 1 > 15 ? 15 : x0 + 1;
    const float* p = Fgl + (size_t)bc * 256;
    float v00 = p[ya * 16 + xa], v01 = p[ya * 16 + xb];
    float v10 = p[yb * 16 + xa], v11 = p[yb * 16 + xb];
    float v0 = v00 + (v01 - v00) * fx;
    float v1 = v10 + (v11 - v10) * fx;
    up[idx] = v0 + (v1 - v0) * fy;
}

// ---------------- K0b: transpose l_w (128x128) -> WT[ci][co] -------------
__global__ __launch_bounds__(256) void k_wt(const float* __restrict__ lw,
                                            float* __restrict__ WT)
{
    int idx = blockIdx.x * 256 + threadIdx.x;   // 16384
    int co = idx & 127, ci = idx >> 7;
    WT[ci * 128 + co] = lw[co * 128 + ci];
}

// ---------------- K7: 1x1 conv (128->128) + BN + ReLU, tiled GEMM --------
// grid: b(8) x ptile(64) = 512 blocks, 256 threads; tile 128co x 64px
__global__ __launch_bounds__(256) void k_lconv(const float* __restrict__ Flg,
                                               const float* __restrict__ up,
                                               const float* __restrict__ WT,
                                               const float* __restrict__ lscale,
                                               const float* __restrict__ lbias,
                                               float* __restrict__ out)
{
    int pt = blockIdx.x & 63, b = blockIdx.x >> 6;
    int p0 = pt * 64;
    __shared__ float Wl[32][128];
    __shared__ float Xl[32][64];
    int t = threadIdx.x;
    int co0 = (t >> 4) * 8, pp = (t & 15) * 4;
    float acc[8][4];
#pragma unroll
    for (int i = 0; i < 8; ++i)
#pragma unroll
        for (int j = 0; j < 4; ++j) acc[i][j] = 0.f;

    for (int kb = 0; kb < 128; kb += 32) {
        for (int idx = t; idx < 4096; idx += 256) {
            int k = idx >> 7, co = idx & 127;
            Wl[k][co] = WT[(kb + k) * 128 + co];
        }
        for (int idx = t; idx < 2048; idx += 256) {
            int k = idx >> 6, p = idx & 63;
            int ci = kb + k;
            const float* src = (ci < 64)
                ? (Flg + ((size_t)b * 64 + ci) * HW_)
                : (up + ((size_t)b * 64 + (ci - 64)) * HW_);
            Xl[k][p] = src[p0 + p];
        }
        __syncthreads();
#pragma unroll
        for (int k = 0; k < 32; ++k) {
            float xr[4], wr[8];
#pragma unroll
            for (int j = 0; j < 4; ++j) xr[j] = Xl[k][pp + j];
#pragma unroll
            for (int i = 0; i < 8; ++i) wr[i] = Wl[k][co0 + i];
#pragma unroll
            for (int i = 0; i < 8; ++i)
#pragma unroll
                for (int j = 0; j < 4; ++j) acc[i][j] += wr[i] * xr[j];
        }
        __syncthreads();
    }
#pragma unroll
    for (int i = 0; i < 8; ++i) {
        int co = co0 + i;
        float sc = lscale[co], bi = lbias[co];
        float4 r4;
        r4.x = fmaxf(acc[i][0] * sc + bi, 0.f);
        r4.y = fmaxf(acc[i][1] * sc + bi, 0.f);
        r4.z = fmaxf(acc[i][2] * sc + bi, 0.f);
        r4.w = fmaxf(acc[i][3] * sc + bi, 0.f);
        *(float4*)(out + ((size_t)b * 128 + co) * HW_ + p0 + pp) = r4;
    }
}

extern "C" void kernel_launch(void* const* d_in, const int* in_sizes, int n_in,
                              void* d_out, int out_size, void* d_ws, size_t ws_size,
                              hipStream_t stream)
{
    const float* inputs    = (const float*)d_in[0];
    const float* dep_w     = (const float*)d_in[1];
    const float* dep_scale = (const float*)d_in[2];
    const float* dep_bias  = (const float*)d_in[3];
    const float* qkv_w     = (const float*)d_in[4];
    const float* qkv_b     = (const float*)d_in[5];
    const float* l_w       = (const float*)d_in[6];
    const float* l_scale   = (const float*)d_in[7];
    const float* l_bias    = (const float*)d_in[8];
    float* out = (float*)d_out;
    float* ws  = (float*)d_ws;

    float* Fl    = ws + OF_FL;
    float* QKVl  = ws + OF_QKVL;
    float* Fg    = ws + OF_FG;
    float* QKVg  = ws + OF_QKVG;
    float* Flg   = ws + OF_FLG;
    float* Fgl   = ws + OF_FGL;
    float* Fglup = ws + OF_FGLUP;
    float* WT    = ws + OF_WT;

    // local branch conv + pool (independent)
    hipLaunchKernelGGL(k_depconv, dim3(256), dim3(256), 0, stream,
                       inputs, dep_w, dep_scale, dep_bias, Fl);
    hipLaunchKernelGGL(k_pool, dim3(512), dim3(256), 0, stream, inputs, Fg);
    hipLaunchKernelGGL(k_wt, dim3(64), dim3(256), 0, stream, l_w, WT);

    // QKV projections
    hipLaunchKernelGGL(k_qkv, dim3(6144), dim3(256), 0, stream,
                       Fl, qkv_w, qkv_b, QKVl, 32768);
    hipLaunchKernelGGL(k_qkv, dim3(384), dim3(256), 0, stream,
                       Fg, qkv_w, qkv_b, QKVg, 2048);

    // cross attentions
    hipLaunchKernelGGL(k_attn_lg, dim3(512), dim3(256), 0, stream,
                       QKVl, QKVg, Flg);
    hipLaunchKernelGGL(k_attn_gl, dim3(256), dim3(256), 0, stream,
                       QKVl, QKVg, Fgl);

    // upsample + fused 1x1 conv
    hipLaunchKernelGGL(k_up, dim3(8192), dim3(256), 0, stream, Fgl, Fglup);
    hipLaunchKernelGGL(k_lconv, dim3(512), dim3(256), 0, stream,
                       Flg, Fglup, WT, l_scale, l_bias, out);
}